// Round 4
// baseline (744.505 us; speedup 1.0000x reference)
//
#include <hip/hip_runtime.h>
#include <cstdint>
#include <cstddef>

// ExllamaLinear: out[M,N] = f16( f16( x[M,K] @ ((q - z) * s)[K,N] ) + bias )
// M = 4096, K = 4096, N = 11008, group 128 along K.
//
// R4 dtype model (per harness header: supported dtypes are bf16/f32/int;
// reference tensors are float16 => stored as FLOAT32 on device, output too):
//   x, scales, bias : const float*   (fp16 values upconverted, fp16-exact)
//   qweight, qzeros : const int32*
//   out             : float*
// GEMM core (unchanged from R3): 128x128 tile, BK=64, 4 waves x (4x4)
// 16x16x32 bf16 MFMA, padded-LDS register staging.

typedef unsigned short u16;
typedef u16    u16x8  __attribute__((ext_vector_type(8)));
typedef __bf16 bfv8   __attribute__((ext_vector_type(8)));
typedef float  f32x4  __attribute__((ext_vector_type(4)));

#define K_DIM 4096
#define N_DIM 11008
#define GS    128
#define LSTR  72   // LDS row stride: 64 data + 8 pad u16 (rows stay 16B-aligned)

__device__ __forceinline__ u16 f2bf(float f) {  // RTNE f32 -> bf16 bits
  union { float f; uint32_t u; } v;
  v.f = f;
  uint32_t u = v.u + 0x7FFFu + ((v.u >> 16) & 1u);
  return (u16)(u >> 16);
}
__device__ __forceinline__ float f16r(float v) {  // fp16 round-trip (RTNE)
  return (float)(_Float16)v;
}

// ---------------------------------------------------------------------------
// Pre-pass A: x f32 -> bf16 bits in workspace. 8 elements/thread.
// ---------------------------------------------------------------------------
__global__ __launch_bounds__(256) void convert_x_kernel(
    const float* __restrict__ x, u16* __restrict__ xb) {
  const size_t i = ((size_t)blockIdx.x * 256 + threadIdx.x) * 8;
  const f32x4 a = *(const f32x4*)(x + i);
  const f32x4 b = *(const f32x4*)(x + i + 4);
  u16x8 o;
#pragma unroll
  for (int t = 0; t < 4; ++t) { o[t] = f2bf(a[t]); o[t + 4] = f2bf(b[t]); }
  *(u16x8*)(xb + i) = o;
}

// ---------------------------------------------------------------------------
// Pre-pass B: dequantize int4 -> Wt[N][K] bf16 bits (transposed).
// Thread owns one (n, 64-wide k-chunk): 8 int32 reads coalesced along n,
// 128 contiguous bytes written along K.
// ---------------------------------------------------------------------------
__global__ __launch_bounds__(256) void dequant_kernel(
    const uint32_t* __restrict__ qweight, const uint32_t* __restrict__ qzeros,
    const float* __restrict__ scales, u16* __restrict__ wt) {
  const int kc = blockIdx.x;                    // 64-wide k chunk: 0..63
  const int n  = blockIdx.y * 256 + threadIdx.x;
  const int g  = kc >> 1;                       // group = kc*64/128

  const uint32_t zq = qzeros[(size_t)g * (N_DIM / 8) + (n >> 3)];
  const int   z   = (int)((zq >> ((n & 7) * 4)) & 15u);
  const float s   = scales[(size_t)g * N_DIM + n];
  const float nzs = -s * (float)z;              // w = fma(q,s,-z*s): exact in f32

  u16* dst = wt + (size_t)n * K_DIM + kc * 64;
  const uint32_t* src = qweight + (size_t)(kc * 8) * N_DIM + n;
#pragma unroll
  for (int j = 0; j < 8; ++j) {
    const uint32_t q = src[(size_t)j * N_DIM];
    u16x8 w;
#pragma unroll
    for (int t = 0; t < 8; ++t) {
      const int qv = (int)((q >> (t * 4)) & 15u);
      w[t] = f2bf(fmaf((float)qv, s, nzs));
    }
    *(u16x8*)(dst + j * 8) = w;
  }
}

// ---------------------------------------------------------------------------
// GEMM: 128x128 tile, BK=64, 4 waves each computing a 64x64 quadrant via
// 4x4 of 16x16x32 bf16 MFMA. Explicit-register staging, padded LDS.
// FUSED=true: no workspace — convert x f32->bf16 and dequantize W in staging.
// ---------------------------------------------------------------------------
template <bool FUSED>
__global__ __launch_bounds__(256) void gemm_kernel(
    const u16* __restrict__ xb, const float* __restrict__ xf,
    const void* __restrict__ wsrc,
    const uint32_t* __restrict__ qzeros, const float* __restrict__ scales,
    const float* __restrict__ bias, float* __restrict__ out) {
  __shared__ __align__(16) u16 As[128 * LSTR];
  __shared__ __align__(16) u16 Bs[128 * LSTR];

  const int tid  = threadIdx.x;
  const int lane = tid & 63;
  const int wave = tid >> 6;
  const int n0 = blockIdx.x * 128;
  const int m0 = blockIdx.y * 128;

  const int m_off = (wave >> 1) * 64;   // wave's 64x64 quadrant
  const int n_off = (wave & 1) * 64;
  const int lrow  = lane & 15;
  const int lk    = lane >> 4;          // k-quad 0..3

  // staging geometry: thread -> (row = i*32 + tid>>3, 16B granule = tid&7)
  const int sm = tid >> 3;              // 0..31
  const int sc = tid & 7;

  const u16*      wt = (const u16*)wsrc;        // !FUSED: Wt[N][K] bf16 bits
  const uint32_t* qw = (const uint32_t*)wsrc;   //  FUSED: qweight[K/8][N]

  f32x4 acc[4][4];
#pragma unroll
  for (int i = 0; i < 4; ++i)
#pragma unroll
    for (int j = 0; j < 4; ++j) acc[i][j] = f32x4{0.f, 0.f, 0.f, 0.f};

  // fused-path per-thread dequant column state
  const int ncol = n0 + (tid & 127);
  float s_cur = 0.f, nzs_cur = 0.f;

  for (int kt = 0; kt < K_DIM / 64; ++kt) {
    const int k0 = kt * 64;

    // ---- stage A ----
    u16x8 av[4];
    if (!FUSED) {
#pragma unroll
      for (int i = 0; i < 4; ++i) {
        const int m = i * 32 + sm;
        av[i] = *(const u16x8*)(xb + (size_t)(m0 + m) * K_DIM + (k0 + sc * 8));
      }
    } else {
#pragma unroll
      for (int i = 0; i < 4; ++i) {
        const int m = i * 32 + sm;
        const float* srcp = xf + (size_t)(m0 + m) * K_DIM + (k0 + sc * 8);
        const f32x4 p = *(const f32x4*)srcp;
        const f32x4 q4 = *(const f32x4*)(srcp + 4);
#pragma unroll
        for (int t = 0; t < 4; ++t) {
          av[i][t] = f2bf(p[t]);
          av[i][t + 4] = f2bf(q4[t]);
        }
      }
    }

    // ---- stage B ----
    u16x8 bv[4];
    if (!FUSED) {
#pragma unroll
      for (int i = 0; i < 4; ++i) {
        const int n = i * 32 + sm;
        bv[i] = *(const u16x8*)(wt + (size_t)(n0 + n) * K_DIM + (k0 + sc * 8));
      }
    } else {
      if ((k0 & (GS - 1)) == 0) {       // new quant group every other K-tile
        const int g = k0 >> 7;
        const uint32_t zq = qzeros[(size_t)g * (N_DIM / 8) + (ncol >> 3)];
        const int z = (int)((zq >> ((ncol & 7) * 4)) & 15u);
        s_cur = scales[(size_t)g * N_DIM + ncol];
        nzs_cur = -s_cur * (float)z;
      }
#pragma unroll
      for (int i = 0; i < 4; ++i) {
        const int k8l = (tid >> 7) + i * 2;     // int32-row 0..7 within K-tile
        const uint32_t q = qw[(size_t)(k0 / 8 + k8l) * N_DIM + ncol];
#pragma unroll
        for (int t = 0; t < 8; ++t) {
          const int qv = (int)((q >> (t * 4)) & 15u);
          bv[i][t] = f2bf(fmaf((float)qv, s_cur, nzs_cur));
        }
      }
    }

    // ---- write stage to LDS ----
#pragma unroll
    for (int i = 0; i < 4; ++i) {
      const int m = i * 32 + sm;
      *(u16x8*)&As[m * LSTR + sc * 8] = av[i];
    }
    if (!FUSED) {
#pragma unroll
      for (int i = 0; i < 4; ++i) {
        const int n = i * 32 + sm;
        *(u16x8*)&Bs[n * LSTR + sc * 8] = bv[i];
      }
    } else {
      const int nl = tid & 127;
#pragma unroll
      for (int i = 0; i < 4; ++i) {
        const int k8l = (tid >> 7) + i * 2;
        *(u16x8*)&Bs[nl * LSTR + k8l * 8] = bv[i];
      }
    }

    __syncthreads();

    // ---- compute: 2 k-steps x 16 MFMA ----
#pragma unroll
    for (int ks = 0; ks < 2; ++ks) {
      const int c = (ks * 4 + lk) * 8;
      bfv8 a[4], b[4];
#pragma unroll
      for (int i = 0; i < 4; ++i)
        a[i] = __builtin_bit_cast(bfv8,
                 *(const u16x8*)&As[(m_off + i * 16 + lrow) * LSTR + c]);
#pragma unroll
      for (int j = 0; j < 4; ++j)
        b[j] = __builtin_bit_cast(bfv8,
                 *(const u16x8*)&Bs[(n_off + j * 16 + lrow) * LSTR + c]);
#pragma unroll
      for (int i = 0; i < 4; ++i)
#pragma unroll
        for (int j = 0; j < 4; ++j)
          acc[i][j] = __builtin_amdgcn_mfma_f32_16x16x32_bf16(a[i], b[j],
                                                              acc[i][j], 0, 0, 0);
    }

    __syncthreads();
  }

  // ---- epilogue: ref rounding f16(f16(acc) + bias); store f32 ----
  // C/D layout (m89-verified): col = lane&15, row = (lane>>4)*4 + reg
#pragma unroll
  for (int j = 0; j < 4; ++j) {
    const int n = n0 + n_off + j * 16 + lrow;
    const float bvf = bias[n];
#pragma unroll
    for (int i = 0; i < 4; ++i) {
      const int mrow = m0 + m_off + i * 16 + lk * 4;
#pragma unroll
      for (int r = 0; r < 4; ++r) {
        out[(size_t)(mrow + r) * N_DIM + n] = f16r(f16r(acc[i][j][r]) + bvf);
      }
    }
  }
}

extern "C" void kernel_launch(void* const* d_in, const int* in_sizes, int n_in,
                              void* d_out, int out_size, void* d_ws, size_t ws_size,
                              hipStream_t stream) {
  // Identify inputs by element count (all five distinct) — immune to order.
  const float* x = nullptr;      const uint32_t* qweight = nullptr;
  const uint32_t* qzeros = nullptr;
  const float* scales = nullptr; const float* bias = nullptr;
  int M = 4096;
  for (int i = 0; i < n_in; ++i) {
    const long long s = in_sizes[i];
    if      (s == (long long)(K_DIM / 8) * N_DIM) qweight = (const uint32_t*)d_in[i];
    else if (s == (long long)(K_DIM / GS) * (N_DIM / 8)) qzeros = (const uint32_t*)d_in[i];
    else if (s == (long long)(K_DIM / GS) * N_DIM) scales = (const float*)d_in[i];
    else if (s == (long long)N_DIM) bias = (const float*)d_in[i];
    else { x = (const float*)d_in[i]; M = (int)(s / K_DIM); }
  }
  float* out = (float*)d_out;

  const size_t xb_bytes = (size_t)M * K_DIM * sizeof(u16);          // 33.5 MB
  const size_t wt_bytes = (size_t)N_DIM * K_DIM * sizeof(u16);      // 90.2 MB

  if (ws_size >= xb_bytes + wt_bytes) {
    u16* xbp = (u16*)d_ws;
    u16* wtp = (u16*)((char*)d_ws + xb_bytes);
    convert_x_kernel<<<(int)((size_t)M * K_DIM / 2048), 256, 0, stream>>>(x, xbp);
    dequant_kernel<<<dim3(K_DIM / 64, N_DIM / 256), 256, 0, stream>>>(
        qweight, qzeros, scales, wtp);
    gemm_kernel<false><<<dim3(N_DIM / 128, M / 128), 256, 0, stream>>>(
        xbp, x, wtp, qzeros, scales, bias, out);
  } else {
    gemm_kernel<true><<<dim3(N_DIM / 128, M / 128), 256, 0, stream>>>(
        nullptr, x, qweight, qzeros, scales, bias, out);
  }
}

// Round 5
// 739.974 us; speedup vs baseline: 1.0061x; 1.0061x over previous
//
#include <hip/hip_runtime.h>
#include <cstdint>
#include <cstddef>

// ExllamaLinear: out[M,N] = f16( f16( x[M,K] @ ((q - z) * s)[K,N] ) + bias )
// M = 4096, K = 4096, N = 11008, group 128 along K. All fp16 tensors are
// stored f32 on device (R4-verified); out is f32.
//
// R5: tiled pre-swizzled workspace layout shared by producer & consumer.
//   xb[mt][kt][g]*8, wt[nt][kt][g]*8  (g in [0,1024), 16B granules)
//   granule g holds row nl=g>>3, k-granule cg=(g&7)^(nl&7)  (XOR bank swizzle)
// GEMM stages A and B with global_load_lds width=16 over fully sequential
// 16KB tile reads (m97 structure); unpadded 32KB LDS; ds_read_b128 fragment
// reads land 2 lanes/bank (free, m136).

typedef unsigned short u16;
typedef u16    u16x8  __attribute__((ext_vector_type(8)));
typedef __bf16 bfv8   __attribute__((ext_vector_type(8)));
typedef float  f32x4  __attribute__((ext_vector_type(4)));

#define K_DIM 4096
#define N_DIM 11008
#define GS    128
#define KT    (K_DIM / 64)   // 64 k-tiles
#define LSTR  72             // fused-fallback padded LDS stride

__device__ __forceinline__ u16 f2bf(float f) {  // RTNE f32 -> bf16 bits
  union { float f; uint32_t u; } v;
  v.f = f;
  uint32_t u = v.u + 0x7FFFu + ((v.u >> 16) & 1u);
  return (u16)(u >> 16);
}
__device__ __forceinline__ float f16r(float v) {  // fp16 round-trip (RTNE)
  return (float)(_Float16)v;
}
__device__ __forceinline__ void async_load16(const u16* g, u16* l) {
  __builtin_amdgcn_global_load_lds(
      (const __attribute__((address_space(1))) uint32_t*)g,
      (__attribute__((address_space(3))) uint32_t*)l, 16, 0, 0);
}

// ---------------------------------------------------------------------------
// Pre-pass A: x f32 -> bf16 bits, tiled+swizzled. One block per (kt, mt) tile;
// writes are perfectly sequential (lane-consecutive 16B granules).
// ---------------------------------------------------------------------------
__global__ __launch_bounds__(256) void convert_x_tiled(
    const float* __restrict__ x, u16* __restrict__ xb) {
  const int kt = blockIdx.x, mt = blockIdx.y;
  const int k0 = kt * 64, m0 = mt * 128;
  u16* dst = xb + ((size_t)(mt * KT + kt)) * 8192;
#pragma unroll
  for (int i = 0; i < 4; ++i) {
    const int g  = i * 256 + threadIdx.x;
    const int nl = g >> 3;
    const int cg = (g & 7) ^ (nl & 7);
    const float* sp = x + (size_t)(m0 + nl) * K_DIM + (k0 + cg * 8);
    const f32x4 p = *(const f32x4*)sp;
    const f32x4 q = *(const f32x4*)(sp + 4);
    u16x8 o;
#pragma unroll
    for (int t = 0; t < 4; ++t) { o[t] = f2bf(p[t]); o[t + 4] = f2bf(q[t]); }
    *(u16x8*)(dst + (size_t)g * 8) = o;
  }
}

// ---------------------------------------------------------------------------
// Pre-pass B: dequantize int4 -> Wt bf16 bits, tiled+swizzled. One granule =
// one qweight int32 (8 nibbles along K). Writes sequential 16B granules.
// ---------------------------------------------------------------------------
__global__ __launch_bounds__(256) void dequant_tiled(
    const uint32_t* __restrict__ qweight, const uint32_t* __restrict__ qzeros,
    const float* __restrict__ scales, u16* __restrict__ wt) {
  const int kt = blockIdx.x, nt = blockIdx.y;
  const int k0 = kt * 64, n0 = nt * 128;
  const int gq = kt >> 1;                       // quant group = k0/128
  u16* dst = wt + ((size_t)(nt * KT + kt)) * 8192;
#pragma unroll
  for (int i = 0; i < 4; ++i) {
    const int g  = i * 256 + threadIdx.x;
    const int nl = g >> 3;
    const int cg = (g & 7) ^ (nl & 7);
    const int n  = n0 + nl;
    const uint32_t zq = qzeros[(size_t)gq * (N_DIM / 8) + (n >> 3)];
    const int   z   = (int)((zq >> ((n & 7) * 4)) & 15u);
    const float s   = scales[(size_t)gq * N_DIM + n];
    const float nzs = -s * (float)z;            // w = fma(q,s,-z*s): exact in f32
    const uint32_t q = qweight[(size_t)(k0 / 8 + cg) * N_DIM + n];
    u16x8 o;
#pragma unroll
    for (int t = 0; t < 8; ++t) {
      const int qv = (int)((q >> (t * 4)) & 15u);
      o[t] = f2bf(fmaf((float)qv, s, nzs));
    }
    *(u16x8*)(dst + (size_t)g * 8) = o;
  }
}

// ---------------------------------------------------------------------------
// GEMM (two-pass): 128x128 tile, BK=64, 4 waves x (4x4) 16x16x32 bf16 MFMA.
// A/B staged by global_load_lds width=16 from sequential tiled layout.
// ---------------------------------------------------------------------------
__global__ __launch_bounds__(256) void gemm_tiled(
    const u16* __restrict__ xb, const u16* __restrict__ wt,
    const float* __restrict__ bias, float* __restrict__ out) {
  __shared__ __align__(16) u16 As[8192];
  __shared__ __align__(16) u16 Bs[8192];

  const int tid  = threadIdx.x;
  const int lane = tid & 63;
  const int wave = tid >> 6;
  const int n0 = blockIdx.x * 128;
  const int m0 = blockIdx.y * 128;

  const int m_off = (wave >> 1) * 64;
  const int n_off = (wave & 1) * 64;
  const int lrow  = lane & 15;
  const int lk    = lane >> 4;          // k-quad 0..3
  const int sw    = lrow & 7;           // XOR swizzle key

  const u16* abase = xb + (size_t)blockIdx.y * KT * 8192;
  const u16* bbase = wt + (size_t)blockIdx.x * KT * 8192;

  f32x4 acc[4][4];
#pragma unroll
  for (int i = 0; i < 4; ++i)
#pragma unroll
    for (int j = 0; j < 4; ++j) acc[i][j] = f32x4{0.f, 0.f, 0.f, 0.f};

  for (int kt = 0; kt < KT; ++kt) {
    const u16* ag = abase + (size_t)kt * 8192;
    const u16* bg = bbase + (size_t)kt * 8192;
#pragma unroll
    for (int i = 0; i < 4; ++i) {
      async_load16(ag + (size_t)(i * 256 + tid) * 8,
                   As + (size_t)(i * 256 + wave * 64) * 8);
      async_load16(bg + (size_t)(i * 256 + tid) * 8,
                   Bs + (size_t)(i * 256 + wave * 64) * 8);
    }
    __syncthreads();

#pragma unroll
    for (int ks = 0; ks < 2; ++ks) {
      const int kq = ks * 4 + lk;
      const int c = (kq ^ sw) * 8;      // swizzled k-granule offset (u16 elems)
      bfv8 a[4], b[4];
#pragma unroll
      for (int i = 0; i < 4; ++i) {
        const int mf = m_off + i * 16 + lrow;
        a[i] = __builtin_bit_cast(bfv8, *(const u16x8*)&As[mf * 64 + c]);
      }
#pragma unroll
      for (int j = 0; j < 4; ++j) {
        const int nf = n_off + j * 16 + lrow;
        b[j] = __builtin_bit_cast(bfv8, *(const u16x8*)&Bs[nf * 64 + c]);
      }
#pragma unroll
      for (int i = 0; i < 4; ++i)
#pragma unroll
        for (int j = 0; j < 4; ++j)
          acc[i][j] = __builtin_amdgcn_mfma_f32_16x16x32_bf16(a[i], b[j],
                                                              acc[i][j], 0, 0, 0);
    }
    __syncthreads();
  }

  // epilogue: ref rounding f16(f16(acc) + bias); store f32.
  // C/D layout (m89): col = lane&15, row = (lane>>4)*4 + reg
#pragma unroll
  for (int j = 0; j < 4; ++j) {
    const int n = n0 + n_off + j * 16 + lrow;
    const float bvf = bias[n];
#pragma unroll
    for (int i = 0; i < 4; ++i) {
      const int mrow = m0 + m_off + i * 16 + lk * 4;
#pragma unroll
      for (int r = 0; r < 4; ++r) {
        out[(size_t)(mrow + r) * N_DIM + n] = f16r(f16r(acc[i][j][r]) + bvf);
      }
    }
  }
}

// ---------------------------------------------------------------------------
// Fused fallback (no workspace): R4 structure, register staging, padded LDS.
// ---------------------------------------------------------------------------
__global__ __launch_bounds__(256) void gemm_fused(
    const float* __restrict__ xf, const uint32_t* __restrict__ qw,
    const uint32_t* __restrict__ qzeros, const float* __restrict__ scales,
    const float* __restrict__ bias, float* __restrict__ out) {
  __shared__ __align__(16) u16 As[128 * LSTR];
  __shared__ __align__(16) u16 Bs[128 * LSTR];

  const int tid  = threadIdx.x;
  const int lane = tid & 63;
  const int wave = tid >> 6;
  const int n0 = blockIdx.x * 128;
  const int m0 = blockIdx.y * 128;
  const int m_off = (wave >> 1) * 64;
  const int n_off = (wave & 1) * 64;
  const int lrow  = lane & 15;
  const int lk    = lane >> 4;
  const int sm = tid >> 3;
  const int sc = tid & 7;

  f32x4 acc[4][4];
#pragma unroll
  for (int i = 0; i < 4; ++i)
#pragma unroll
    for (int j = 0; j < 4; ++j) acc[i][j] = f32x4{0.f, 0.f, 0.f, 0.f};

  const int ncol = n0 + (tid & 127);
  float s_cur = 0.f, nzs_cur = 0.f;

  for (int kt = 0; kt < KT; ++kt) {
    const int k0 = kt * 64;
    u16x8 av[4];
#pragma unroll
    for (int i = 0; i < 4; ++i) {
      const int m = i * 32 + sm;
      const float* sp = xf + (size_t)(m0 + m) * K_DIM + (k0 + sc * 8);
      const f32x4 p = *(const f32x4*)sp;
      const f32x4 q4 = *(const f32x4*)(sp + 4);
#pragma unroll
      for (int t = 0; t < 4; ++t) { av[i][t] = f2bf(p[t]); av[i][t+4] = f2bf(q4[t]); }
    }
    u16x8 bv[4];
    if ((k0 & (GS - 1)) == 0) {
      const int g = k0 >> 7;
      const uint32_t zq = qzeros[(size_t)g * (N_DIM / 8) + (ncol >> 3)];
      const int z = (int)((zq >> ((ncol & 7) * 4)) & 15u);
      s_cur = scales[(size_t)g * N_DIM + ncol];
      nzs_cur = -s_cur * (float)z;
    }
#pragma unroll
    for (int i = 0; i < 4; ++i) {
      const int k8l = (tid >> 7) + i * 2;
      const uint32_t q = qw[(size_t)(k0 / 8 + k8l) * N_DIM + ncol];
#pragma unroll
      for (int t = 0; t < 8; ++t) {
        const int qv = (int)((q >> (t * 4)) & 15u);
        bv[i][t] = f2bf(fmaf((float)qv, s_cur, nzs_cur));
      }
    }
#pragma unroll
    for (int i = 0; i < 4; ++i)
      *(u16x8*)&As[(i * 32 + sm) * LSTR + sc * 8] = av[i];
    {
      const int nl = tid & 127;
#pragma unroll
      for (int i = 0; i < 4; ++i) {
        const int k8l = (tid >> 7) + i * 2;
        *(u16x8*)&Bs[nl * LSTR + k8l * 8] = bv[i];
      }
    }
    __syncthreads();
#pragma unroll
    for (int ks = 0; ks < 2; ++ks) {
      const int c = (ks * 4 + lk) * 8;
      bfv8 a[4], b[4];
#pragma unroll
      for (int i = 0; i < 4; ++i)
        a[i] = __builtin_bit_cast(bfv8,
                 *(const u16x8*)&As[(m_off + i * 16 + lrow) * LSTR + c]);
#pragma unroll
      for (int j = 0; j < 4; ++j)
        b[j] = __builtin_bit_cast(bfv8,
                 *(const u16x8*)&Bs[(n_off + j * 16 + lrow) * LSTR + c]);
#pragma unroll
      for (int i = 0; i < 4; ++i)
#pragma unroll
        for (int j = 0; j < 4; ++j)
          acc[i][j] = __builtin_amdgcn_mfma_f32_16x16x32_bf16(a[i], b[j],
                                                              acc[i][j], 0, 0, 0);
    }
    __syncthreads();
  }
#pragma unroll
  for (int j = 0; j < 4; ++j) {
    const int n = n0 + n_off + j * 16 + lrow;
    const float bvf = bias[n];
#pragma unroll
    for (int i = 0; i < 4; ++i) {
      const int mrow = m0 + m_off + i * 16 + lk * 4;
#pragma unroll
      for (int r = 0; r < 4; ++r)
        out[(size_t)(mrow + r) * N_DIM + n] = f16r(f16r(acc[i][j][r]) + bvf);
    }
  }
}

extern "C" void kernel_launch(void* const* d_in, const int* in_sizes, int n_in,
                              void* d_out, int out_size, void* d_ws, size_t ws_size,
                              hipStream_t stream) {
  // Identify inputs by element count (all five distinct).
  const float* x = nullptr;      const uint32_t* qweight = nullptr;
  const uint32_t* qzeros = nullptr;
  const float* scales = nullptr; const float* bias = nullptr;
  int M = 4096;
  for (int i = 0; i < n_in; ++i) {
    const long long s = in_sizes[i];
    if      (s == (long long)(K_DIM / 8) * N_DIM) qweight = (const uint32_t*)d_in[i];
    else if (s == (long long)(K_DIM / GS) * (N_DIM / 8)) qzeros = (const uint32_t*)d_in[i];
    else if (s == (long long)(K_DIM / GS) * N_DIM) scales = (const float*)d_in[i];
    else if (s == (long long)N_DIM) bias = (const float*)d_in[i];
    else { x = (const float*)d_in[i]; M = (int)(s / K_DIM); }
  }
  float* out = (float*)d_out;

  const size_t xb_bytes = (size_t)M * K_DIM * sizeof(u16);      // 33.5 MB
  const size_t wt_bytes = (size_t)N_DIM * K_DIM * sizeof(u16);  // 90.2 MB

  if (ws_size >= xb_bytes + wt_bytes) {
    u16* xbp = (u16*)d_ws;
    u16* wtp = (u16*)((char*)d_ws + xb_bytes);
    convert_x_tiled<<<dim3(KT, M / 128), 256, 0, stream>>>(x, xbp);
    dequant_tiled<<<dim3(KT, N_DIM / 128), 256, 0, stream>>>(
        qweight, qzeros, scales, wtp);
    gemm_tiled<<<dim3(N_DIM / 128, M / 128), 256, 0, stream>>>(
        xbp, wtp, bias, out);
  } else {
    gemm_fused<<<dim3(N_DIM / 128, M / 128), 256, 0, stream>>>(
        x, qweight, qzeros, scales, bias, out);
  }
}